// Round 3
// baseline (1059.770 us; speedup 1.0000x reference)
//
#include <hip/hip_runtime.h>
#include <cstdint>
#include <cstddef>

// GRU (reset_after) + dense(1)+sigmoid, masked by per-batch length t.
// ONE WAVE per sequence: 512 blocks x 64 threads, 1 wave/SIMD (latency-optimal:
// wall time = longest sequence's chain latency).
// Lane j owns gate columns {j, 64+j, 128+j}: U (3x64) + W (3x24) pre-paired in
// VGPRs for v_pk_fma_f32. h broadcast via same-wave LDS write->read (no barriers).
// Per-step output partial -> LDS; batched transposed reduce once per 64-step
// chunk (NO per-step shfl chain). rcp intrinsic instead of precise fp division.

typedef float v2f __attribute__((ext_vector_type(2)));
typedef float v4f __attribute__((ext_vector_type(4)));

__device__ __forceinline__ void pkfma(v2f& acc, const v2f a, const v2f b) {
    // acc += a * b (packed 2xfp32, single VOP3P instruction)
    asm("v_pk_fma_f32 %0, %1, %2, %0" : "+v"(acc) : "v"(a), "v"(b));
}

__device__ __forceinline__ float fsigmoid(float x) {
    // 1/(1+e^-x) via v_exp + v_rcp (err ~1ulp each; tolerance is 1.17e-2)
    return __builtin_amdgcn_rcpf(1.f + __expf(-x));
}

__global__ __launch_bounds__(64, 1) void gru_wave_kernel(
    const float* __restrict__ xg,      // (512,1024,24)
    const int*   __restrict__ tg,      // (512,)
    const float* __restrict__ Wg,      // (24,192)
    const float* __restrict__ Ug,      // (64,192)
    const float* __restrict__ bg,      // (2,192)
    const float* __restrict__ Wdg,     // (64,1)
    const float* __restrict__ bdg,     // (1,)
    float*       __restrict__ outg)    // (512,1024)
{
    const int b = blockIdx.x;
    const int j = threadIdx.x;          // lane 0..63

    __shared__ __align__(16) float xbuf[1536];      // 64 steps x 24 floats
    __shared__ __align__(16) float h_lds[64];
    __shared__ __align__(16) float p_lds[64 * 66];  // [step][lane], stride 66 (pad)
    __shared__ float o_last;

    const int   t    = tg[b];
    float*      outb = outg + (size_t)b * 1024;
    const float bdv  = bdg[0];

    if (t <= 0) {
        const float fill = fsigmoid(bdv);
        for (int i = j; i < 1024; i += 64) outb[i] = fill;
        return;
    }

    // ---- weight preload: pre-paired along reduction dim for pk_fma ----
    v2f Uz[32], Ur[32], Uc[32];
    #pragma unroll
    for (int k = 0; k < 32; ++k) {
        const float* r0 = Ug + (2 * k)     * 192;
        const float* r1 = Ug + (2 * k + 1) * 192;
        Uz[k] = (v2f){ r0[j],       r1[j]       };
        Ur[k] = (v2f){ r0[64 + j],  r1[64 + j]  };
        Uc[k] = (v2f){ r0[128 + j], r1[128 + j] };
    }
    v2f Wz[12], Wr[12], Wc[12];
    #pragma unroll
    for (int d = 0; d < 12; ++d) {
        const float* r0 = Wg + (2 * d)     * 192;
        const float* r1 = Wg + (2 * d + 1) * 192;
        Wz[d] = (v2f){ r0[j],       r1[j]       };
        Wr[d] = (v2f){ r0[64 + j],  r1[64 + j]  };
        Wc[d] = (v2f){ r0[128 + j], r1[128 + j] };
    }
    // z/r pre-activations use b0+b1 summed; c keeps them separate.
    const float bz  = bg[j]       + bg[192 + j];
    const float br  = bg[64 + j]  + bg[256 + j];
    const float b0c = bg[128 + j];
    const float b1c = bg[320 + j];
    const float wdj = Wdg[j];

    const float* xb = xg + (size_t)b * 24576;   // 1024*24

    // ---- stage chunk 0; prefetch chunk 1 into registers ----
    {
        const v4f* src = (const v4f*)xb;
        v4f st[6];
        #pragma unroll
        for (int i = 0; i < 6; ++i) st[i] = src[i * 64 + j];
        v4f* dst = (v4f*)xbuf;
        #pragma unroll
        for (int i = 0; i < 6; ++i) dst[i * 64 + j] = st[i];
    }
    v4f pf[6];
    if (t > 64) {
        const v4f* nsrc = (const v4f*)(xb + 1536);
        #pragma unroll
        for (int i = 0; i < 6; ++i) pf[i] = nsrc[i * 64 + j];
    }
    h_lds[j] = 0.f;

    float hold = 0.f;   // lane j's own h_j

    for (int base = 0; base < t; base += 64) {
        const int cnt = (t - base < 64) ? (t - base) : 64;

        // ---- chunk boundary: commit prefetched x, start next prefetch ----
        if (base > 0) {
            v4f* dst = (v4f*)xbuf;
            #pragma unroll
            for (int i = 0; i < 6; ++i) dst[i * 64 + j] = pf[i];
            if (base + 64 < t) {
                const v4f* nsrc = (const v4f*)(xb + (size_t)(base + 64) * 24);
                #pragma unroll
                for (int i = 0; i < 6; ++i) pf[i] = nsrc[i * 64 + j];
            }
        }

        for (int c = 0; c < cnt; ++c) {
            // h broadcast (16 ds_read_b128, all-lane broadcast = conflict-free)
            const v4f* hr = (const v4f*)h_lds;
            // x row for this step (24 floats, 16B-aligned: c*96 bytes)
            const v4f* xr = (const v4f*)(xbuf + c * 24);
            v4f xv[6];
            #pragma unroll
            for (int i = 0; i < 6; ++i) xv[i] = xr[i];

            v2f za  = (v2f){ bz,  0.f };
            v2f ra  = (v2f){ br,  0.f };
            v2f ca  = (v2f){ b1c, 0.f };
            v2f xca = (v2f){ b0c, 0.f };

            #pragma unroll
            for (int i = 0; i < 16; ++i) {
                const v4f h = hr[i];
                pkfma(za, Uz[2 * i], h.lo); pkfma(za, Uz[2 * i + 1], h.hi);
                pkfma(ra, Ur[2 * i], h.lo); pkfma(ra, Ur[2 * i + 1], h.hi);
                pkfma(ca, Uc[2 * i], h.lo); pkfma(ca, Uc[2 * i + 1], h.hi);
            }
            #pragma unroll
            for (int i = 0; i < 6; ++i) {
                pkfma(za,  Wz[2 * i], xv[i].lo); pkfma(za,  Wz[2 * i + 1], xv[i].hi);
                pkfma(ra,  Wr[2 * i], xv[i].lo); pkfma(ra,  Wr[2 * i + 1], xv[i].hi);
                pkfma(xca, Wc[2 * i], xv[i].lo); pkfma(xca, Wc[2 * i + 1], xv[i].hi);
            }

            const float zp = za.x + za.y;
            const float rp = ra.x + ra.y;
            const float hc = ca.x + ca.y;
            const float xc = xca.x + xca.y;

            const float z  = fsigmoid(zp);
            const float r  = fsigmoid(rp);
            // tanh(y) = 1 - 2/(1+e^(2y))
            const float cg = 1.f - 2.f * __builtin_amdgcn_rcpf(
                                 1.f + __expf(2.f * fmaf(r, hc, xc)));
            const float hn = fmaf(z, hold - cg, cg);   // z*h + (1-z)*c

            hold = hn;
            h_lds[j] = hn;                   // next step's broadcast source
            p_lds[c * 66 + j] = hn * wdj;    // output partial (reduced per chunk)
        }

        // ---- batched transposed reduce: lane j handles step c = j ----
        // (same-wave LDS ordering guarantees p writes precede these reads)
        if (j < cnt) {
            const v2f* pr = (const v2f*)(p_lds + j * 66);
            v2f s2 = (v2f){ 0.f, 0.f };
            #pragma unroll
            for (int i = 0; i < 32; ++i) s2 += pr[i];
            const float o = fsigmoid(s2.x + s2.y + bdv);
            outb[base + j] = o;
            if (j == cnt - 1) o_last = o;
        }
    }

    // ---- constant tail fill (h frozen for s >= t) ----
    const float fill = o_last;
    for (int i = t + j; i < 1024; i += 64) outb[i] = fill;
}

extern "C" void kernel_launch(void* const* d_in, const int* in_sizes, int n_in,
                              void* d_out, int out_size, void* d_ws, size_t ws_size,
                              hipStream_t stream) {
    (void)in_sizes; (void)n_in; (void)d_ws; (void)ws_size; (void)out_size;
    const float* x  = (const float*)d_in[0];
    const int*   t  = (const int*)d_in[1];
    const float* W  = (const float*)d_in[2];
    const float* U  = (const float*)d_in[3];
    const float* bb = (const float*)d_in[4];
    const float* Wd = (const float*)d_in[5];
    const float* bd = (const float*)d_in[6];
    float* out = (float*)d_out;

    hipLaunchKernelGGL(gru_wave_kernel, dim3(512), dim3(64), 0, stream,
                       x, t, W, U, bb, Wd, bd, out);
}

// Round 4
// 553.541 us; speedup vs baseline: 1.9145x; 1.9145x over previous
//
#include <hip/hip_runtime.h>
#include <cstdint>
#include <cstddef>

// GRU (reset_after) + dense(1)+sigmoid, masked by per-batch length t.
// R4: 2 waves x 64 lanes per sequence (512 blocks x 128 threads).
// Wave w owns h-columns [32w, 32w+32); lane's k-half (ln>>5) splits the
// reduction dim (U: 64 -> 2x32, W: 24 -> 2x12). All three gates of a column
// are computed in the SAME wave -> no cross-wave z/r traffic; halves combine
// via 4 independent __shfl_xor(32). h double-buffered in LDS -> ONE
// __syncthreads per step. rcp-based sigmoids. Chunked output reduce.

typedef float v2f __attribute__((ext_vector_type(2)));
typedef float v4f __attribute__((ext_vector_type(4)));

__device__ __forceinline__ void pkfma(v2f& acc, const v2f a, const v2f b) {
    // acc += a * b (packed 2xfp32, single VOP3P instruction)
    asm("v_pk_fma_f32 %0, %1, %2, %0" : "+v"(acc) : "v"(a), "v"(b));
}

__device__ __forceinline__ float fsigmoid(float x) {
    // 1/(1+e^-x) via v_exp + v_rcp (err ~1ulp; tolerance is 1.17e-2)
    return __builtin_amdgcn_rcpf(1.f + __expf(-x));
}

#define NT 128

__global__ __launch_bounds__(NT, 1) void gru2_kernel(
    const float* __restrict__ xg,      // (512,1024,24)
    const int*   __restrict__ tg,      // (512,)
    const float* __restrict__ Wg,      // (24,192)
    const float* __restrict__ Ug,      // (64,192)
    const float* __restrict__ bg,      // (2,192)
    const float* __restrict__ Wdg,     // (64,1)
    const float* __restrict__ bdg,     // (1,)
    float*       __restrict__ outg)    // (512,1024)
{
    const int b    = blockIdx.x;
    const int tid  = threadIdx.x;
    const int wv   = tid >> 6;              // wave 0/1
    const int ln   = tid & 63;
    const int half = ln >> 5;               // k-half 0/1
    const int cj   = (wv << 5) + (ln & 31); // owned h column 0..63

    __shared__ __align__(16) float xbuf[1536];      // 64 steps x 24 floats
    __shared__ __align__(16) float h_lds[2][64];    // double-buffered state
    __shared__ __align__(16) float p_lds[64 * 66];  // [step][col], pad 66
    __shared__ float o_last;

    const int   t    = tg[b];
    float*      outb = outg + (size_t)b * 1024;
    const float bdv  = bdg[0];

    if (t <= 0) {
        const float fill = fsigmoid(bdv);
        for (int i = tid; i < 1024; i += NT) outb[i] = fill;
        return;
    }

    // ---- weight preload: this lane's k-half of columns {cj, 64+cj, 128+cj},
    //      pre-paired along the reduction dim for pk_fma ----
    v2f Uz[16], Ur[16], Uc[16];
    #pragma unroll
    for (int k = 0; k < 16; ++k) {
        const float* r0 = Ug + (half * 32 + 2 * k)     * 192;
        const float* r1 = Ug + (half * 32 + 2 * k + 1) * 192;
        Uz[k] = (v2f){ r0[cj],       r1[cj]       };
        Ur[k] = (v2f){ r0[64 + cj],  r1[64 + cj]  };
        Uc[k] = (v2f){ r0[128 + cj], r1[128 + cj] };
    }
    v2f Wz[6], Wr[6], Wc[6];
    #pragma unroll
    for (int d = 0; d < 6; ++d) {
        const float* r0 = Wg + (half * 12 + 2 * d)     * 192;
        const float* r1 = Wg + (half * 12 + 2 * d + 1) * 192;
        Wz[d] = (v2f){ r0[cj],       r1[cj]       };
        Wr[d] = (v2f){ r0[64 + cj],  r1[64 + cj]  };
        Wc[d] = (v2f){ r0[128 + cj], r1[128 + cj] };
    }
    // biases added AFTER the cross-half combine (avoid double count)
    const float bz  = bg[cj]       + bg[192 + cj];
    const float br  = bg[64 + cj]  + bg[256 + cj];
    const float b0c = bg[128 + cj];
    const float b1c = bg[320 + cj];
    const float wdj = Wdg[cj];

    const float* xb = xg + (size_t)b * 24576;   // 1024*24

    // ---- stage chunk 0 (384 v4f / 128 threads = 3 each); zero h buf 0 ----
    {
        const v4f* src = (const v4f*)xb;
        v4f s0 = src[tid], s1 = src[tid + 128], s2 = src[tid + 256];
        v4f* dst = (v4f*)xbuf;
        dst[tid] = s0; dst[tid + 128] = s1; dst[tid + 256] = s2;
    }
    if (tid < 64) h_lds[0][tid] = 0.f;
    v4f pf0, pf1, pf2;
    if (t > 64) {
        const v4f* ns = (const v4f*)(xb + 1536);
        pf0 = ns[tid]; pf1 = ns[tid + 128]; pf2 = ns[tid + 256];
    }
    __syncthreads();

    float hold = 0.f;   // this lane's column state h_cj (kept redundantly per half)

    for (int base = 0; base < t; base += 64) {
        const int cnt = (t - base < 64) ? (t - base) : 64;

        if (base > 0) {
            // previous chunk fully done (step barrier). Commit prefetched x,
            // reduce previous chunk's outputs, then prefetch next chunk.
            v4f* dst = (v4f*)xbuf;
            dst[tid] = pf0; dst[tid + 128] = pf1; dst[tid + 256] = pf2;
            if (tid < 64) {
                const v2f* pr = (const v2f*)(p_lds + tid * 66);
                v2f s2 = (v2f){0.f, 0.f};
                #pragma unroll
                for (int i = 0; i < 32; ++i) s2 += pr[i];
                outb[base - 64 + tid] = fsigmoid(s2.x + s2.y + bdv);
            }
            __syncthreads();   // xbuf + reduce complete before reuse
            if (base + 64 < t) {
                const v4f* ns = (const v4f*)(xb + (size_t)(base + 64) * 24);
                pf0 = ns[tid]; pf1 = ns[tid + 128]; pf2 = ns[tid + 256];
            }
        }

        for (int c = 0; c < cnt; ++c) {
            const int rb = c & 1;          // read h buffer (written last step)
            // this lane's k-half of h (8 v4f) and of x row c (3 v4f)
            const v4f* hr = (const v4f*)(h_lds[rb] + (half << 5));
            const v4f* xr = (const v4f*)(xbuf + c * 24 + half * 12);

            v2f za = (v2f){0.f, 0.f}, ra = za, ca = za, xca = za;
            #pragma unroll
            for (int i = 0; i < 8; ++i) {
                const v4f h = hr[i];
                pkfma(za, Uz[2 * i], h.lo); pkfma(za, Uz[2 * i + 1], h.hi);
                pkfma(ra, Ur[2 * i], h.lo); pkfma(ra, Ur[2 * i + 1], h.hi);
                pkfma(ca, Uc[2 * i], h.lo); pkfma(ca, Uc[2 * i + 1], h.hi);
            }
            #pragma unroll
            for (int i = 0; i < 3; ++i) {
                const v4f x = xr[i];
                pkfma(za,  Wz[2 * i], x.lo); pkfma(za,  Wz[2 * i + 1], x.hi);
                pkfma(ra,  Wr[2 * i], x.lo); pkfma(ra,  Wr[2 * i + 1], x.hi);
                pkfma(xca, Wc[2 * i], x.lo); pkfma(xca, Wc[2 * i + 1], x.hi);
            }

            // horizontal + cross-half combine (4 independent shuffles, pipelined)
            float zs  = za.x + za.y;
            float rs  = ra.x + ra.y;
            float hcs = ca.x + ca.y;
            float xcs = xca.x + xca.y;
            zs  += __shfl_xor(zs, 32, 64);
            rs  += __shfl_xor(rs, 32, 64);
            hcs += __shfl_xor(hcs, 32, 64);
            xcs += __shfl_xor(xcs, 32, 64);

            const float z  = fsigmoid(zs + bz);
            const float r  = fsigmoid(rs + br);
            // tanh(y) = 1 - 2/(1+e^(2y)); y = (xc+b0c) + r*(hc+b1c)
            const float cg = 1.f - 2.f * __builtin_amdgcn_rcpf(
                                 1.f + __expf(2.f * fmaf(r, hcs + b1c, xcs + b0c)));
            const float hn = fmaf(z, hold - cg, cg);   // z*h + (1-z)*c
            hold = hn;

            if (half == 0) {                    // single writer per column
                h_lds[rb ^ 1][cj]  = hn;        // next step's state buffer
                p_lds[c * 66 + cj] = hn * wdj;  // output partial
            }
            __syncthreads();   // ONE barrier per step: h'/p visible
        }
    }

    // ---- final (possibly partial) chunk reduce ----
    const int lastbase = ((t - 1) >> 6) << 6;
    const int lastcnt  = t - lastbase;
    if (tid < lastcnt) {
        const v2f* pr = (const v2f*)(p_lds + tid * 66);
        v2f s2 = (v2f){0.f, 0.f};
        #pragma unroll
        for (int i = 0; i < 32; ++i) s2 += pr[i];
        const float o = fsigmoid(s2.x + s2.y + bdv);
        outb[lastbase + tid] = o;
        if (tid == lastcnt - 1) o_last = o;
    }
    __syncthreads();
    // ---- constant tail fill (h frozen for s >= t) ----
    const float fill = o_last;
    for (int i = t + tid; i < 1024; i += NT) outb[i] = fill;
}

extern "C" void kernel_launch(void* const* d_in, const int* in_sizes, int n_in,
                              void* d_out, int out_size, void* d_ws, size_t ws_size,
                              hipStream_t stream) {
    (void)in_sizes; (void)n_in; (void)d_ws; (void)ws_size; (void)out_size;
    const float* x  = (const float*)d_in[0];
    const int*   t  = (const int*)d_in[1];
    const float* W  = (const float*)d_in[2];
    const float* U  = (const float*)d_in[3];
    const float* bb = (const float*)d_in[4];
    const float* Wd = (const float*)d_in[5];
    const float* bd = (const float*)d_in[6];
    float* out = (float*)d_out;

    hipLaunchKernelGGL(gru2_kernel, dim3(512), dim3(NT), 0, stream,
                       x, t, W, U, bb, Wd, bd, out);
}